// Round 2
// baseline (72.258 us; speedup 1.0000x reference)
//
#include <hip/hip_runtime.h>
#include <math.h>

// CapsuleLayer dynamic routing, fused single kernel. Round 2: occupancy.
// B=8, I=32, C=8, HW=256, O=16, h=16, NUM_ROUTING=3.
// Grid 512 blocks (b = blk>>6, hw0 = (blk&63)*4), block = 512 thr = 8 waves.
//   wave w: owns i-slice [4w, 4w+4)  -> votes v[4][4] = 64 VGPRs
//   lane l: owns m = 4l..4l+3 (o = l>>2, h-quad = l&3)
// 4 waves/SIMD (vs 2 in R1): __launch_bounds__(512,4) caps VGPR at 128.

__device__ __forceinline__ float4 f4zero() { return make_float4(0.f, 0.f, 0.f, 0.f); }

__device__ __forceinline__ void fma4(float4& a, float s, const float4& q) {
    a.x = fmaf(s, q.x, a.x); a.y = fmaf(s, q.y, a.y);
    a.z = fmaf(s, q.z, a.z); a.w = fmaf(s, q.w, a.w);
}

__device__ __forceinline__ void add4(float4& a, const float4& q) {
    a.x += q.x; a.y += q.y; a.z += q.z; a.w += q.w;
}

__global__ __launch_bounds__(512, 4)
void caps_kernel(const float* __restrict__ x,
                 const float* __restrict__ wgt,
                 const float* __restrict__ bias,
                 float* __restrict__ out)
{
    __shared__ float s_route [4 * 512];    // [p][i][o]   8 KB
    __shared__ float s_logits[4 * 512];    // [p][i][o]   8 KB
    __shared__ float s_part  [8 * 4 * 256];// [w][p][m]  32 KB
    __shared__ float s_act   [4 * 256];    // [p][m]      4 KB   => 52 KB total

    const int t   = threadIdx.x;
    const int w   = t >> 6;                  // wave 0..7
    const int l   = t & 63;
    const int b   = blockIdx.x >> 6;
    const int hw0 = (blockIdx.x & 63) << 2;

    const float4 bias4 = ((const float4*)bias)[l];

    // ---- votes: v[ii][p] = sum_c x[b, 4w+ii, c, hw0+p] * W[4w+ii, c, 4l..4l+3]
    float4 v[4][4];
    {
        const float*  xb = x + (size_t)b * 65536 + hw0;
        const float4* w4 = (const float4*)wgt;
        #pragma unroll
        for (int ii = 0; ii < 4; ++ii) {
            const int i = __builtin_amdgcn_readfirstlane((w << 2) + ii); // SGPR -> s_load for x
            #pragma unroll
            for (int p = 0; p < 4; ++p) v[ii][p] = f4zero();
            #pragma unroll
            for (int c = 0; c < 8; ++c) {
                const float4 wv = w4[i * 512 + c * 64 + l];                 // coalesced dwordx4
                const float4 xv = *(const float4*)(xb + (i * 8 + c) * 256); // wave-uniform
                fma4(v[ii][0], xv.x, wv);
                fma4(v[ii][1], xv.y, wv);
                fma4(v[ii][2], xv.z, wv);
                fma4(v[ii][3], xv.w, wv);
            }
        }
    }

    float4 actreg = f4zero();
    const int o  = l >> 2;       // this lane's output capsule
    const int pw = w & 3;        // pixel this wave combines/squashes

    #pragma unroll
    for (int it = 0; it < 3; ++it) {
        float4 pre[4];
        if (it == 0) {
            // softmax(0) == 1/16 exactly
            #pragma unroll
            for (int p = 0; p < 4; ++p) {
                float4 s = v[0][p];
                #pragma unroll
                for (int ii = 1; ii < 4; ++ii) add4(s, v[ii][p]);
                pre[p] = make_float4(s.x * 0.0625f, s.y * 0.0625f,
                                     s.z * 0.0625f, s.w * 0.0625f);
            }
        } else {
            // softmax over o. 128 rows (p,i); wave w owns rows [16w,16w+16),
            // row = 16w + (l>>2), lane quad member l&3 covers o-quad 4*(l&3).
            const int row  = (w << 4) + (l >> 2);
            const int base = row * 16 + ((l & 3) << 2);
            const float4 lg = *(const float4*)&s_logits[base];
            float mx = fmaxf(fmaxf(lg.x, lg.y), fmaxf(lg.z, lg.w));
            mx = fmaxf(mx, __shfl_xor(mx, 1));
            mx = fmaxf(mx, __shfl_xor(mx, 2));
            const float e0 = __expf(lg.x - mx), e1 = __expf(lg.y - mx);
            const float e2 = __expf(lg.z - mx), e3 = __expf(lg.w - mx);
            float sm = (e0 + e1) + (e2 + e3);
            sm += __shfl_xor(sm, 1);
            sm += __shfl_xor(sm, 2);
            const float inv = 1.f / sm;
            *(float4*)&s_route[base] = make_float4(e0 * inv, e1 * inv, e2 * inv, e3 * inv);
            __syncthreads();  // route visible to all waves

            #pragma unroll
            for (int p = 0; p < 4; ++p) pre[p] = f4zero();
            #pragma unroll
            for (int ii = 0; ii < 4; ++ii) {
                const int i = (w << 2) + ii;
                #pragma unroll
                for (int p = 0; p < 4; ++p) {
                    const float r = s_route[p * 512 + i * 16 + o];  // quad-broadcast read
                    fma4(pre[p], r, v[ii][p]);
                }
            }
        }

        // stage this wave's partial preacts for all 4 pixels
        #pragma unroll
        for (int p = 0; p < 4; ++p)
            *(float4*)&s_part[(w * 4 + p) * 256 + 4 * l] = pre[p];
        __syncthreads();  // B1

        // combine across 8 waves for pixel pw, add bias, squash
        float4 acc = bias4;
        #pragma unroll
        for (int wp = 0; wp < 8; ++wp)
            add4(acc, *(const float4*)&s_part[(wp * 4 + pw) * 256 + 4 * l]);
        float sq = acc.x * acc.x + acc.y * acc.y + acc.z * acc.z + acc.w * acc.w;
        sq += __shfl_xor(sq, 1);
        sq += __shfl_xor(sq, 2);                 // full ||s||^2 over 16 h
        const float f = sqrtf(sq) / (1.f + sq);  // s/||s|| * ||s||^2/(1+||s||^2)
        actreg = make_float4(acc.x * f, acc.y * f, acc.z * f, acc.w * f);

        if (it < 2) {
            if (w < 4) *(float4*)&s_act[w * 256 + 4 * l] = actreg;  // waves 0-3 publish
            __syncthreads();  // B2

            // distances[p][i][o] = dot_h(votes, act[p]) ; lane keeps pixel l&3
            float dacc[4] = {0.f, 0.f, 0.f, 0.f};
            #pragma unroll
            for (int p = 0; p < 4; ++p) {
                const float4 a = *(const float4*)&s_act[p * 256 + 4 * l];
                #pragma unroll
                for (int ii = 0; ii < 4; ++ii) {
                    float d = v[ii][p].x * a.x + v[ii][p].y * a.y
                            + v[ii][p].z * a.z + v[ii][p].w * a.w;
                    d += __shfl_xor(d, 1);
                    d += __shfl_xor(d, 2);       // full dot over 16 h
                    dacc[ii] = ((l & 3) == p) ? d : dacc[ii];
                }
            }
            const int lb = (l & 3) * 512 + (w << 2) * 16 + o;  // [p=l&3][i=4w+ii][o]
            if (it == 0) {
                #pragma unroll
                for (int ii = 0; ii < 4; ++ii) s_logits[lb + ii * 16] = dacc[ii];
            } else {
                #pragma unroll
                for (int ii = 0; ii < 4; ++ii) s_logits[lb + ii * 16] += dacc[ii];
            }
            __syncthreads();  // B3
        }
    }

    // ---- output: out[b, m, hw0..hw0+3] as float4, one thread per m
    if (w < 4) *(float4*)&s_act[w * 256 + 4 * l] = actreg;  // final act, pixel w
    __syncthreads();
    if (t < 256) {
        float4 o4;
        o4.x = s_act[t];
        o4.y = s_act[256 + t];
        o4.z = s_act[512 + t];
        o4.w = s_act[768 + t];
        *(float4*)(out + (size_t)b * 65536 + (size_t)t * 256 + hw0) = o4;
    }
}

extern "C" void kernel_launch(void* const* d_in, const int* in_sizes, int n_in,
                              void* d_out, int out_size, void* d_ws, size_t ws_size,
                              hipStream_t stream) {
    const float* x    = (const float*)d_in[0];   // (8,32,8,16,16)
    const float* wgt  = (const float*)d_in[1];   // (32,8,256)
    const float* bias = (const float*)d_in[2];   // (16,16,1,1)
    float* out = (float*)d_out;                  // (8,16,16,16,16)
    caps_kernel<<<dim3(512), dim3(512), 0, stream>>>(x, wgt, bias, out);
}